// Round 6
// baseline (824.106 us; speedup 1.0000x reference)
//
#include <hip/hip_runtime.h>
#include <math.h>

#define B_ 2
#define N_ 16384
#define V_ 10475
#define J_ 55
#define K_ 6

constexpr int   NB      = 512;       // z-bins per batch
constexpr int   SSTRIDE = 16384;     // sorted-array stride (pos fits 14 bits)
constexpr float ZLO     = -6.0f;     // clamped edge bins => correct for any data
constexpr float ZHI     =  6.0f;
constexpr float HBIN    = (ZHI - ZLO) / (float)NB;
constexpr float INVH    = (float)NB / (ZHI - ZLO);
constexpr int   SUB     = 4;         // subthreads per point

__device__ __forceinline__ int zbin(float z) {
    float t = (z - ZLO) * INVH;
    int b = (int)floorf(t);
    return min(max(b, 0), NB - 1);
}

// ---------------------------------------------------------------------------
__global__ __launch_bounds__(1024) void zero_kernel(int* __restrict__ binCnt) {
    int i = threadIdx.x;            // 1 block of 1024 == B_*NB
    binCnt[i] = 0;
}

__global__ __launch_bounds__(256) void hist_kernel(const float* __restrict__ pverts,
                                                   int* __restrict__ binCnt) {
    int i = blockIdx.x * 256 + threadIdx.x;
    if (i >= B_ * V_) return;
    int b = i / V_;
    atomicAdd(&binCnt[b * NB + zbin(pverts[i * 3 + 2])], 1);
}

__global__ __launch_bounds__(NB) void scan_kernel(const int* __restrict__ binCnt,
                                                  int* __restrict__ binStart,
                                                  int* __restrict__ binCur) {
    __shared__ int s[NB];
    int b = blockIdx.x, t = threadIdx.x;
    int c = binCnt[b * NB + t];
    s[t] = c;
    __syncthreads();
    for (int off = 1; off < NB; off <<= 1) {
        int v = (t >= off) ? s[t - off] : 0;
        __syncthreads();
        s[t] += v;
        __syncthreads();
    }
    int st = s[t] - c;                       // exclusive
    binStart[b * (NB + 1) + t] = st;
    binCur[b * NB + t] = st;
    if (t == NB - 1) binStart[b * (NB + 1) + NB] = s[t];
}

__global__ __launch_bounds__(256) void scatter_kernel(const float* __restrict__ pverts,
                                                      int* __restrict__ binCur,
                                                      float4* __restrict__ pvs,
                                                      int* __restrict__ vidx) {
    int i = blockIdx.x * 256 + threadIdx.x;
    if (i >= B_ * V_) return;
    int b = i / V_;
    int vi = i - b * V_;
    float vx = pverts[i * 3 + 0], vy = pverts[i * 3 + 1], vz = pverts[i * 3 + 2];
    int pos = atomicAdd(&binCur[b * NB + zbin(vz)], 1);
    pvs[b * SSTRIDE + pos] = make_float4(vx, vy, vz, vx * vx + vy * vy + vz * vz);
    vidx[b * SSTRIDE + pos] = vi;
}

// ---------------------------------------------------------------------------
// KNN: thread = (point, subthread q of 4). Scans z-bins outward from the
// point's bin; each subthread takes verts stride-4 within each bin, keeping a
// branchless sorted top-8 pool of packed keys ((d2+1e-4)[31:14] | sortedpos).
// Stop rule (exact, see analysis): skip/stop when frontier dz^2 >= f6_up,
// f6_up = upper band edge of this subthread's 6th-best key. Pools of the 4
// adjacent lanes merged via 2-stage keep-8 bitonic; 8 keys written per point.
// ---------------------------------------------------------------------------
__global__ __launch_bounds__(256) void knn_kernel(const float4* __restrict__ pvs,
                                                  const int* __restrict__ binStart,
                                                  const float* __restrict__ x,
                                                  const float* __restrict__ cam,
                                                  unsigned int* __restrict__ outK) {
    int tid = blockIdx.x * 256 + threadIdx.x;    // 0 .. B_*N_*SUB
    int p = tid >> 2, q = tid & 3;
    int b = p >> 14;

    const float cs = cam[b * 3 + 0], ctx = cam[b * 3 + 1], cty = cam[b * 3 + 2];
    const float Px = x[p * 3 + 0] / cs - ctx;
    const float Py = x[p * 3 + 1] / cs - cty;
    const float Pz = x[p * 3 + 2] / cs;
    const float Ax = -2.f * Px, Ay = -2.f * Py, Az = -2.f * Pz;
    const float Cc = Px * Px + Py * Py + Pz * Pz + 1.0e-4f;  // bias > f32 err

    unsigned int bK[8];
#pragma unroll
    for (int t = 0; t < 8; ++t) bK[t] = 0xFFFFFFFFu;

    const float4* pb = pvs + b * SSTRIDE;
    const int* bs = binStart + b * (NB + 1);

    int c0 = (int)floorf((Pz - ZLO) * INVH);
    int jL = min(max(c0, 0), NB - 1);
    int jR = jL + 1;

    for (int guard = 0; guard < NB + 2; ++guard) {
        float f6up = __uint_as_float(bK[5] | 0x3FFFu);   // NaN while unfilled
        bool okL = jL >= 0, okR = jR < NB;
        if (!okL && !okR) break;
        // left bound uses bin's upper edge (valid even for clamped bin 0);
        // jL==NB-1 forced to 0 (its verts may be clamped from above).
        float dzL = okL ? ((jL >= NB - 1) ? 0.f
                         : fmaxf(0.f, Pz - (ZLO + (float)(jL + 1) * HBIN)))
                        : 3.0e38f;
        float dzR = okR ? fmaxf(0.f, (ZLO + (float)jR * HBIN) - Pz) : 3.0e38f;
        bool useL = dzL <= dzR;
        float dz = useL ? dzL : dzR;
        if (dz * dz >= f6up) break;                      // NaN-safe
        int j = useL ? jL : jR;
        if (useL) --jL; else ++jR;

        int en = bs[j + 1];
        for (int i = bs[j] + q; i < en; i += SUB) {
            float4 qv = pb[i];
            float d2 = fmaf(Ax, qv.x, fmaf(Ay, qv.y, fmaf(Az, qv.z, Cc + qv.w)));
            unsigned int key = (__float_as_uint(d2) & 0xFFFFC000u)
                             | (unsigned int)i;          // SSTRIDE = 2^14
            if (key < bK[7]) {
                unsigned int kk = key;
#pragma unroll
                for (int t = 0; t < 8; ++t) {
                    unsigned int mn = min(kk, bK[t]);
                    kk = max(kk, bK[t]);
                    bK[t] = mn;
                }
            }
        }
    }

    // merge the 4 subthread pools (adjacent lanes) -> top-8 of the union
    unsigned int E[8];
#pragma unroll
    for (int t = 0; t < 8; ++t) E[t] = bK[t];
#pragma unroll
    for (int s = 1; s <= 2; s <<= 1) {
        unsigned int Bt[8], Cv[8];
#pragma unroll
        for (int t = 0; t < 8; ++t) Bt[t] = (unsigned int)__shfl_xor((int)E[t], s, 64);
#pragma unroll
        for (int t = 0; t < 8; ++t) Cv[t] = min(E[t], Bt[7 - t]);
#define CE_(a, c) { unsigned int mn_ = min(Cv[a], Cv[c]); Cv[c] = max(Cv[a], Cv[c]); Cv[a] = mn_; }
        CE_(0, 4) CE_(1, 5) CE_(2, 6) CE_(3, 7)
        CE_(0, 2) CE_(1, 3) CE_(4, 6) CE_(5, 7)
        CE_(0, 1) CE_(2, 3) CE_(4, 5) CE_(6, 7)
#undef CE_
#pragma unroll
        for (int t = 0; t < 8; ++t) E[t] = Cv[t];
    }
    outK[p * 8 + q * 2 + 0] = E[q * 2 + 0];
    outK[p * 8 + q * 2 + 1] = E[q * 2 + 1];
}

// ---------------------------------------------------------------------------
__device__ __forceinline__ double shfl_d(double v, int src) {
    int lo = __double2loint(v), hi = __double2hiint(v);
    lo = __shfl(lo, src, 64);
    hi = __shfl(hi, src, 64);
    return __hiloint2double(hi, lo);
}

// Epilogue (wave-per-point, R5-proven path): f64 re-rank of the 8 candidates
// with the reference's expanded formula + stable (d, idx) sort, then
// conf/weights/blend/apply.
__global__ __launch_bounds__(256) void epilogue_kernel(const float4* __restrict__ pvs,
                                                       const int* __restrict__ vidx,
                                                       const unsigned int* __restrict__ outK,
                                                       const float* __restrict__ x,
                                                       const float* __restrict__ cam,
                                                       const float* __restrict__ lbs,
                                                       const float* __restrict__ vt,
                                                       float* __restrict__ out) {
    const int lane = threadIdx.x & 63, wid = threadIdx.x >> 6;
    const int p = blockIdx.x * 4 + wid;
    const int b = p >> 14;

    const float cs = cam[b * 3 + 0], ctx = cam[b * 3 + 1], cty = cam[b * 3 + 2];
    const float Px = x[p * 3 + 0] / cs - ctx;
    const float Py = x[p * 3 + 1] / cs - cty;
    const float Pz = x[p * 3 + 2] / cs;

    double myd = 1.0e300;
    int mygi = 0x7FFFFFFF;
    if (lane < 8) {
        unsigned int key = outK[p * 8 + lane];
        if (key != 0xFFFFFFFFu) {
            int pos = (int)(key & 0x3FFFu);
            mygi = vidx[b * SSTRIDE + pos];
            float4 vq = pvs[b * SSTRIDE + pos];
            const double csd = (double)cs;
            const double PX = (double)x[p * 3 + 0] / csd - (double)ctx;
            const double PY = (double)x[p * 3 + 1] / csd - (double)cty;
            const double PZ = (double)x[p * 3 + 2] / csd;
            double vx = (double)vq.x, vy = (double)vq.y, vz = (double)vq.z;
            double v2 = vx * vx + vy * vy + vz * vz;
            double P2 = PX * PX + PY * PY + PZ * PZ;
            double dot = PX * vx + PY * vy + PZ * vz;
            myd = P2 + v2 - 2.0 * dot;          // reference expanded form
        }
    }
    double dd[8];
    int ii[8];
#pragma unroll
    for (int t = 0; t < 8; ++t) { dd[t] = shfl_d(myd, t); ii[t] = __shfl(mygi, t, 64); }
#define CE_(a, c) { \
        bool sw_ = (dd[a] > dd[c]) || (dd[a] == dd[c] && ii[a] > ii[c]); \
        double dt_ = sw_ ? dd[a] : dd[c]; dd[a] = sw_ ? dd[c] : dd[a]; dd[c] = dt_; \
        int it_ = sw_ ? ii[a] : ii[c]; ii[a] = sw_ ? ii[c] : ii[a]; ii[c] = it_; }
#pragma unroll
    for (int r = 0; r < 4; ++r) {
        CE_(0, 1) CE_(2, 3) CE_(4, 5) CE_(6, 7)
        CE_(1, 2) CE_(3, 4) CE_(5, 6)
    }
#undef CE_

    // ---- fused epilogue (f32: decisions have huge margins; passed R5) ----
    const int i0 = (ii[0] < V_) ? ii[0] : 0;
    float r0v = (lane < J_) ? lbs[i0 * J_ + lane] : 0.f;
    float wgt[K_];
    wgt[0] = expf(-fmaxf((float)dd[0], 0.f));
#pragma unroll
    for (int k = 1; k < K_; ++k) {
        int gk = (ii[k] < V_) ? ii[k] : 0;
        float rkv = (lane < J_) ? lbs[gk * J_ + lane] : 0.f;
        float sv = fabsf(rkv - r0v);
#pragma unroll
        for (int m = 1; m <= 32; m <<= 1) sv += __shfl_xor(sv, m, 64);
        // conf > 0.9  <=>  ssum < -WSTD2*ln(0.9) = 0.0021072103
        wgt[k] = (sv < 0.0021072103f) ? expf(-fmaxf((float)dd[k], 0.f)) : 0.f;
    }
    float wsum = ((wgt[0] + wgt[1]) + (wgt[2] + wgt[3])) + (wgt[4] + wgt[5]);
    float inv = 1.f / wsum;

    float acc = 0.f;
    if (lane < 16) {
#pragma unroll
        for (int k = 0; k < K_; ++k) {
            int gk = (ii[k] < V_) ? ii[k] : 0;
            acc += (wgt[k] * inv) * vt[((size_t)(b * V_ + gk)) * 16 + lane];
        }
    }
    const int c = lane & 3;
    float pc = (c == 0) ? Px : (c == 1) ? Py : (c == 2) ? Pz : 1.f;
    float part = acc * pc;
    part += __shfl_xor(part, 1, 64);
    part += __shfl_xor(part, 2, 64);
    if (lane == 0)      out[p * 3 + 0] = part;
    else if (lane == 4) out[p * 3 + 1] = part;
    else if (lane == 8) out[p * 3 + 2] = part;
}

// ---------------------------------------------------------------------------
extern "C" void kernel_launch(void* const* d_in, const int* in_sizes, int n_in,
                              void* d_out, int out_size, void* d_ws, size_t ws_size,
                              hipStream_t stream) {
    const float* x      = (const float*)d_in[0];  // [B,N,3]
    const float* cam    = (const float*)d_in[1];  // [B,3]
    const float* lbs    = (const float*)d_in[2];  // [V,J]
    const float* vt     = (const float*)d_in[3];  // [B,V,4,4]
    const float* pverts = (const float*)d_in[4];  // [B,V,3]
    float* out = (float*)d_out;                   // [B,N,3]

    char* ws = (char*)d_ws;
    int*    binCnt   = (int*)ws;                                  // B*NB
    int*    binStart = binCnt + B_ * NB;                          // B*(NB+1)
    int*    binCur   = binStart + B_ * (NB + 1);                  // B*NB
    float4* pvs      = (float4*)(ws + 16384);                     // B*SSTRIDE f4 (512KB)
    int*    vidx     = (int*)((char*)pvs + (size_t)B_ * SSTRIDE * 16);   // 128KB
    unsigned int* outK = (unsigned int*)((char*)vidx + (size_t)B_ * SSTRIDE * 4); // 1MB

    zero_kernel<<<1, 1024, 0, stream>>>(binCnt);
    hist_kernel<<<(B_ * V_ + 255) / 256, 256, 0, stream>>>(pverts, binCnt);
    scan_kernel<<<B_, NB, 0, stream>>>(binCnt, binStart, binCur);
    scatter_kernel<<<(B_ * V_ + 255) / 256, 256, 0, stream>>>(pverts, binCur, pvs, vidx);
    knn_kernel<<<(B_ * N_ * SUB) / 256, 256, 0, stream>>>(pvs, binStart, x, cam, outK);
    epilogue_kernel<<<B_ * N_ / 4, 256, 0, stream>>>(pvs, vidx, outK, x, cam, lbs, vt, out);
}

// Round 7
// 266.650 us; speedup vs baseline: 3.0906x; 3.0906x over previous
//
#include <hip/hip_runtime.h>
#include <math.h>

#define B_ 2
#define N_ 16384
#define V_ 10475
#define J_ 55
#define K_ 6

constexpr int   NB      = 512;       // z-bins per batch
constexpr int   SSTRIDE = 16384;     // sorted-array stride (pos fits 14 bits)
constexpr float ZLO     = -6.0f;
constexpr float ZHI     =  6.0f;
constexpr float HBIN    = (ZHI - ZLO) / (float)NB;
constexpr float INVH    = (float)NB / (ZHI - ZLO);

__device__ __forceinline__ int zbin(float z) {
    int b = (int)floorf((z - ZLO) * INVH);
    return min(max(b, 0), NB - 1);
}

// ---------------------------------------------------------------------------
// Build: zero(counts) -> hist(verts+points) -> scan(4 arrays) -> scatter
// ---------------------------------------------------------------------------
__global__ __launch_bounds__(1024) void zero_kernel(int* __restrict__ binCntAll) {
    int i = blockIdx.x * 1024 + threadIdx.x;     // 2 * B_ * NB = 2048
    if (i < 2 * B_ * NB) binCntAll[i] = 0;
}

__global__ __launch_bounds__(256) void hist_kernel(const float* __restrict__ pverts,
                                                   const float* __restrict__ x,
                                                   const float* __restrict__ cam,
                                                   int* __restrict__ binCntV,
                                                   int* __restrict__ binCntP) {
    int i = blockIdx.x * 256 + threadIdx.x;
    if (i < B_ * V_) {
        int b = i / V_;
        atomicAdd(&binCntV[b * NB + zbin(pverts[i * 3 + 2])], 1);
    }
    int j = i - B_ * V_;
    if (j >= 0 && j < B_ * N_) {
        int b = j >> 14;
        float z = x[j * 3 + 2] / cam[b * 3 + 0];
        atomicAdd(&binCntP[b * NB + zbin(z)], 1);
    }
}

__global__ __launch_bounds__(NB) void scan_kernel(const int* __restrict__ binCntV,
                                                  const int* __restrict__ binCntP,
                                                  int* __restrict__ binStartV,
                                                  int* __restrict__ binStartP,
                                                  int* __restrict__ binCurV,
                                                  int* __restrict__ binCurP) {
    __shared__ int s[NB];
    int blk = blockIdx.x, t = threadIdx.x;
    const int* cnt;
    int *start, *cur;
    if (blk < 2) { cnt = binCntV + blk * NB; start = binStartV + blk * (NB + 1); cur = binCurV + blk * NB; }
    else         { cnt = binCntP + (blk - 2) * NB; start = binStartP + (blk - 2) * (NB + 1); cur = binCurP + (blk - 2) * NB; }
    int c = cnt[t];
    s[t] = c;
    __syncthreads();
    for (int off = 1; off < NB; off <<= 1) {
        int v = (t >= off) ? s[t - off] : 0;
        __syncthreads();
        s[t] += v;
        __syncthreads();
    }
    int st = s[t] - c;
    start[t] = st;
    cur[t] = st;
    if (t == NB - 1) start[NB] = s[t];
}

__global__ __launch_bounds__(256) void scatter_kernel(const float* __restrict__ pverts,
                                                      const float* __restrict__ x,
                                                      const float* __restrict__ cam,
                                                      int* __restrict__ binCurV,
                                                      int* __restrict__ binCurP,
                                                      float4* __restrict__ pvs,
                                                      int* __restrict__ vidx,
                                                      int* __restrict__ vbin,
                                                      int* __restrict__ psort) {
    int i = blockIdx.x * 256 + threadIdx.x;
    if (i < B_ * V_) {
        int b = i / V_;
        int vi = i - b * V_;
        float vx = pverts[i * 3 + 0], vy = pverts[i * 3 + 1], vz = pverts[i * 3 + 2];
        int bin = zbin(vz);
        int pos = atomicAdd(&binCurV[b * NB + bin], 1);
        pvs[b * SSTRIDE + pos] = make_float4(vx, vy, vz, vx * vx + vy * vy + vz * vz);
        vidx[b * SSTRIDE + pos] = vi;         // batch-local vert id
        vbin[b * SSTRIDE + pos] = bin;
    }
    int j = i - B_ * V_;
    if (j >= 0 && j < B_ * N_) {
        int b = j >> 14;
        float z = x[j * 3 + 2] / cam[b * 3 + 0];
        int pos = atomicAdd(&binCurP[b * NB + zbin(z)], 1);
        psort[b * N_ + pos] = j;              // global point id
    }
}

// ---------------------------------------------------------------------------
// KNN: block = 64 z-adjacent points (lane-per-point), 16 waves scan broadcast
// LDS tiles of the z-sorted vert array. Center window 2048 verts; block gate
// G = max over points of union-6th key band-top (conservative: pools only
// improve); expand 1024-vert chunks while frontier bin-edge dz^2 < G.
// Keys: (d2+1e-4)[31:14] | sortedpos[13:0]; f64 re-rank happens in epilogue.
// ---------------------------------------------------------------------------
__global__ __launch_bounds__(1024, 8) void knn_kernel(const float4* __restrict__ pvs,
                                                      const int* __restrict__ vbin,
                                                      const int* __restrict__ binStartV,
                                                      const int* __restrict__ psort,
                                                      const float* __restrict__ x,
                                                      const float* __restrict__ cam,
                                                      unsigned int* __restrict__ outK) {
    __shared__ float4 tile[2048];
    __shared__ unsigned int cK[16][64][6];
    __shared__ float gateG;

    const int tid = threadIdx.x, lane = tid & 63, wid = tid >> 6;
    const int b   = blockIdx.x >> 8;              // 256 blocks per batch
    const int blk = blockIdx.x & 255;
    const int pid = psort[b * N_ + blk * 64 + lane];   // global point id

    const float cs = cam[b * 3 + 0], ctx = cam[b * 3 + 1], cty = cam[b * 3 + 2];
    const float Px = x[pid * 3 + 0] / cs - ctx;
    const float Py = x[pid * 3 + 1] / cs - cty;
    const float Pz = x[pid * 3 + 2] / cs;
    const float Ax = -2.f * Px, Ay = -2.f * Py, Az = -2.f * Pz;
    const float Cc = Px * Px + Py * Py + Pz * Pz + 1.0e-4f;  // bias > f32 err

    // block z extent (identical in every wave: same 64 points per lane)
    float zmin = Pz, zmax = Pz;
#pragma unroll
    for (int m = 1; m <= 32; m <<= 1) {
        zmin = fminf(zmin, __shfl_xor(zmin, m, 64));
        zmax = fmaxf(zmax, __shfl_xor(zmax, m, 64));
    }

    // center window [lo, hi) of 2048 sorted positions
    const int* bs = binStartV + b * (NB + 1);
    int cbin = zbin(0.5f * (zmin + zmax));
    int center = (bs[cbin] + bs[cbin + 1]) >> 1;
    int lo = center - 1024;
    lo = max(0, min(lo, V_ - 2048));
    int hi = lo + 2048;

    unsigned int bK[6];
#pragma unroll
    for (int t = 0; t < 6; ++t) bK[t] = 0xFFFFFFFFu;

    const float4* pb = pvs + b * SSTRIDE;
    const int* vbn = vbin + b * SSTRIDE;

#define SCAN_RANGE(RL, CNT)                                                    \
    for (int i = wid; i < (CNT); i += 16) {                                    \
        float4 q = tile[i];            /* wave-uniform addr: broadcast */      \
        float d2 = fmaf(Ax, q.x, fmaf(Ay, q.y, fmaf(Az, q.z, Cc + q.w)));      \
        unsigned int key = (__float_as_uint(d2) & 0xFFFFC000u)                 \
                         | (unsigned int)((RL) + i);                           \
        if (key < bK[5]) {                                                     \
            unsigned int kk = key;                                             \
            _Pragma("unroll")                                                  \
            for (int t = 0; t < 6; ++t) {                                      \
                unsigned int mn = min(kk, bK[t]);                              \
                kk = max(kk, bK[t]);                                           \
                bK[t] = mn;                                                    \
            }                                                                  \
        }                                                                      \
    }

    // ---- stage + scan center window ----
    tile[tid]        = pb[lo + tid];
    tile[tid + 1024] = pb[lo + 1024 + tid];
    __syncthreads();
    SCAN_RANGE(lo, 2048)

    // ---- gate: per-point union-6th (exact over 16 pools), block max ----
#pragma unroll
    for (int t = 0; t < 6; ++t) cK[wid][lane][t] = bK[t];
    __syncthreads();
    if (wid == 0) {
        unsigned int U[6];
#pragma unroll
        for (int t = 0; t < 6; ++t) U[t] = 0xFFFFFFFFu;
        for (int ss = 0; ss < 16; ++ss)
#pragma unroll
            for (int t = 0; t < 6; ++t) {
                unsigned int kk = cK[ss][lane][t];
                if (kk < U[5]) {
#pragma unroll
                    for (int u = 0; u < 6; ++u) {
                        unsigned int mn = min(kk, U[u]);
                        kk = max(kk, U[u]);
                        U[u] = mn;
                    }
                }
            }
        float g = __uint_as_float(U[5] | 0x3FFFu);   // band top (finite: >=6 real)
#pragma unroll
        for (int m = 1; m <= 32; m <<= 1)
            g = fmaxf(g, __shfl_xor(g, m, 64));
        if (lane == 0) gateG = g;
    }
    __syncthreads();
    const float G = gateG;

    // ---- expansion: 1024-vert chunks while frontier bound beats G ----
    // Bounds use bin edges of the frontier position's bin (monotone outward);
    // clamped edge bins forced to 0 (verts may lie beyond the grid).
    while (true) {
        float bl = 3.0e38f, br = 3.0e38f;
        if (lo > 0) {
            int j = __builtin_amdgcn_readfirstlane(vbn[lo - 1]);
            bl = (j >= NB - 1) ? 0.f
               : fmaxf(0.f, zmin - (ZLO + (float)(j + 1) * HBIN));
        }
        if (hi < V_) {
            int j = __builtin_amdgcn_readfirstlane(vbn[hi]);
            br = (j <= 0) ? 0.f
               : fmaxf(0.f, (ZLO + (float)j * HBIN) - zmax);
        }
        bool canL = (lo > 0)  && (bl * bl < G);
        bool canR = (hi < V_) && (br * br < G);
        if (!canL && !canR) break;
        bool left = canL && (!canR || bl <= br);
        int rl, rh;
        if (left) { rh = lo; rl = max(0, lo - 1024); lo = rl; }
        else      { rl = hi; rh = min(V_, hi + 1024); hi = rh; }
        __syncthreads();                 // previous tile fully consumed
        int cnt = rh - rl;
        if (tid < cnt) tile[tid] = pb[rl + tid];
        __syncthreads();
        SCAN_RANGE(rl, cnt)
    }
#undef SCAN_RANGE

    // ---- final: write pools, wave0 merges 96 -> top-8 keys, store ----
    __syncthreads();
#pragma unroll
    for (int t = 0; t < 6; ++t) cK[wid][lane][t] = bK[t];
    __syncthreads();
    if (wid == 0) {
        unsigned int E[8];
#pragma unroll
        for (int t = 0; t < 8; ++t) E[t] = 0xFFFFFFFFu;
        for (int ss = 0; ss < 16; ++ss)
#pragma unroll
            for (int t = 0; t < 6; ++t) {
                unsigned int kk = cK[ss][lane][t];
                if (kk < E[7]) {
#pragma unroll
                    for (int u = 0; u < 8; ++u) {
                        unsigned int mn = min(kk, E[u]);
                        kk = max(kk, E[u]);
                        E[u] = mn;
                    }
                }
            }
#pragma unroll
        for (int t = 0; t < 8; ++t) outK[(size_t)pid * 8 + t] = E[t];
    }
}

// ---------------------------------------------------------------------------
__device__ __forceinline__ double shfl_d(double v, int src) {
    int lo = __double2loint(v), hi = __double2hiint(v);
    lo = __shfl(lo, src, 64);
    hi = __shfl(hi, src, 64);
    return __hiloint2double(hi, lo);
}

// Epilogue (R6-proven): wave-per-point f64 re-rank of the 8 candidates with
// the reference's expanded formula + stable (d, idx) sort, then
// conf/weights/blend/apply.
__global__ __launch_bounds__(256) void epilogue_kernel(const float4* __restrict__ pvs,
                                                       const int* __restrict__ vidx,
                                                       const unsigned int* __restrict__ outK,
                                                       const float* __restrict__ x,
                                                       const float* __restrict__ cam,
                                                       const float* __restrict__ lbs,
                                                       const float* __restrict__ vt,
                                                       float* __restrict__ out) {
    const int lane = threadIdx.x & 63, wid = threadIdx.x >> 6;
    const int p = blockIdx.x * 4 + wid;
    const int b = p >> 14;

    const float cs = cam[b * 3 + 0], ctx = cam[b * 3 + 1], cty = cam[b * 3 + 2];
    const float Px = x[p * 3 + 0] / cs - ctx;
    const float Py = x[p * 3 + 1] / cs - cty;
    const float Pz = x[p * 3 + 2] / cs;

    double myd = 1.0e300;
    int mygi = 0x7FFFFFFF;
    if (lane < 8) {
        unsigned int key = outK[(size_t)p * 8 + lane];
        if (key != 0xFFFFFFFFu) {
            int pos = (int)(key & 0x3FFFu);
            mygi = vidx[b * SSTRIDE + pos];
            float4 vq = pvs[b * SSTRIDE + pos];
            const double csd = (double)cs;
            const double PX = (double)x[p * 3 + 0] / csd - (double)ctx;
            const double PY = (double)x[p * 3 + 1] / csd - (double)cty;
            const double PZ = (double)x[p * 3 + 2] / csd;
            double vx = (double)vq.x, vy = (double)vq.y, vz = (double)vq.z;
            double v2 = vx * vx + vy * vy + vz * vz;
            double P2 = PX * PX + PY * PY + PZ * PZ;
            double dot = PX * vx + PY * vy + PZ * vz;
            myd = P2 + v2 - 2.0 * dot;          // reference expanded form
        }
    }
    double dd[8];
    int ii[8];
#pragma unroll
    for (int t = 0; t < 8; ++t) { dd[t] = shfl_d(myd, t); ii[t] = __shfl(mygi, t, 64); }
#define CE_(a, c) { \
        bool sw_ = (dd[a] > dd[c]) || (dd[a] == dd[c] && ii[a] > ii[c]); \
        double dt_ = sw_ ? dd[a] : dd[c]; dd[a] = sw_ ? dd[c] : dd[a]; dd[c] = dt_; \
        int it_ = sw_ ? ii[a] : ii[c]; ii[a] = sw_ ? ii[c] : ii[a]; ii[c] = it_; }
#pragma unroll
    for (int r = 0; r < 4; ++r) {
        CE_(0, 1) CE_(2, 3) CE_(4, 5) CE_(6, 7)
        CE_(1, 2) CE_(3, 4) CE_(5, 6)
    }
#undef CE_

    const int i0 = (ii[0] < V_) ? ii[0] : 0;
    float r0v = (lane < J_) ? lbs[i0 * J_ + lane] : 0.f;
    float wgt[K_];
    wgt[0] = expf(-fmaxf((float)dd[0], 0.f));
#pragma unroll
    for (int k = 1; k < K_; ++k) {
        int gk = (ii[k] < V_) ? ii[k] : 0;
        float rkv = (lane < J_) ? lbs[gk * J_ + lane] : 0.f;
        float sv = fabsf(rkv - r0v);
#pragma unroll
        for (int m = 1; m <= 32; m <<= 1) sv += __shfl_xor(sv, m, 64);
        // conf > 0.9  <=>  ssum < -WSTD2*ln(0.9) = 0.0021072103
        wgt[k] = (sv < 0.0021072103f) ? expf(-fmaxf((float)dd[k], 0.f)) : 0.f;
    }
    float wsum = ((wgt[0] + wgt[1]) + (wgt[2] + wgt[3])) + (wgt[4] + wgt[5]);
    float inv = 1.f / wsum;

    float acc = 0.f;
    if (lane < 16) {
#pragma unroll
        for (int k = 0; k < K_; ++k) {
            int gk = (ii[k] < V_) ? ii[k] : 0;
            acc += (wgt[k] * inv) * vt[((size_t)(b * V_ + gk)) * 16 + lane];
        }
    }
    const int c = lane & 3;
    float pc = (c == 0) ? Px : (c == 1) ? Py : (c == 2) ? Pz : 1.f;
    float part = acc * pc;
    part += __shfl_xor(part, 1, 64);
    part += __shfl_xor(part, 2, 64);
    if (lane == 0)      out[p * 3 + 0] = part;
    else if (lane == 4) out[p * 3 + 1] = part;
    else if (lane == 8) out[p * 3 + 2] = part;
}

// ---------------------------------------------------------------------------
extern "C" void kernel_launch(void* const* d_in, const int* in_sizes, int n_in,
                              void* d_out, int out_size, void* d_ws, size_t ws_size,
                              hipStream_t stream) {
    const float* x      = (const float*)d_in[0];  // [B,N,3]
    const float* cam    = (const float*)d_in[1];  // [B,3]
    const float* lbs    = (const float*)d_in[2];  // [V,J]
    const float* vt     = (const float*)d_in[3];  // [B,V,4,4]
    const float* pverts = (const float*)d_in[4];  // [B,V,3]
    float* out = (float*)d_out;                   // [B,N,3]

    char* ws = (char*)d_ws;
    int* binCntV   = (int*)ws;                          // 2*512      @0
    int* binCntP   = binCntV + B_ * NB;                 // 2*512
    int* binStartV = binCntP + B_ * NB;                 // 2*513
    int* binStartP = binStartV + B_ * (NB + 1);         // 2*513
    int* binCurV   = binStartP + B_ * (NB + 1);         // 2*512
    int* binCurP   = binCurV + B_ * NB;                 // 2*512
    char* p16 = (char*)(binCurP + B_ * NB);
    size_t off = ((size_t)(p16 - ws) + 15) & ~(size_t)15;
    float4* pvs = (float4*)(ws + off);                  // B*SSTRIDE*16 = 512KB
    int* vidx  = (int*)((char*)pvs + (size_t)B_ * SSTRIDE * 16);   // 128KB
    int* vbin  = vidx + B_ * SSTRIDE;                   // 128KB
    int* psort = vbin + B_ * SSTRIDE;                   // 128KB
    unsigned int* outK = (unsigned int*)(psort + B_ * N_);         // 1MB

    const int histTotal = B_ * V_ + B_ * N_;
    zero_kernel<<<2, 1024, 0, stream>>>(binCntV);
    hist_kernel<<<(histTotal + 255) / 256, 256, 0, stream>>>(pverts, x, cam, binCntV, binCntP);
    scan_kernel<<<4, NB, 0, stream>>>(binCntV, binCntP, binStartV, binStartP, binCurV, binCurP);
    scatter_kernel<<<(histTotal + 255) / 256, 256, 0, stream>>>(pverts, x, cam, binCurV, binCurP,
                                                                pvs, vidx, vbin, psort);
    knn_kernel<<<B_ * (N_ / 64), 1024, 0, stream>>>(pvs, vbin, binStartV, psort, x, cam, outK);
    epilogue_kernel<<<B_ * N_ / 4, 256, 0, stream>>>(pvs, vidx, outK, x, cam, lbs, vt, out);
}